// Round 4
// baseline (169.237 us; speedup 1.0000x reference)
//
#include <hip/hip_runtime.h>

#define NG 76
#define NPOS (NG * NG)              // 5776
#define NC 85                       // 5 + 80
#define NA 3
#define NPB 192                     // positions per full tile -> 768 B per row
#define TILES_MAIN (NPOS / NPB)     // 30
#define POS_TAIL (TILES_MAIN * NPB) // 5760
#define NPB_TAIL (NPOS - POS_TAIL)  // 16
#define TPP (TILES_MAIN + 1)        // 31
#define NT 1024
#define STRIDE_F 8.0f               // 608 / 76

typedef float f4 __attribute__((ext_vector_type(4)));

// exp(w) * scaled_anchor * stride == exp(w) * ANCHOR  (scaled = ANCHOR/stride)
__constant__ float c_aw[NA] = {10.0f, 16.0f, 33.0f};
__constant__ float c_ah[NA] = {13.0f, 30.0f, 23.0f};

__device__ __forceinline__ float rcpf(float x) { return __builtin_amdgcn_rcpf(x); }

template<int Q, int NIT>
__device__ __forceinline__ void process_tile(const float* __restrict__ in_plane,
                                             float* __restrict__ out_block,
                                             float* lds, int pos0,
                                             float aw, float ah, int t) {
    constexpr int NV = NC * Q;                       // f4 vectors in the tile

    // ---- load: NIT f4/thread issued back-to-back (deep MLP). Q=48 ->
    // each wave-load covers one contiguous ~768 B run of a channel row,
    // vs 8x128 B scattered before: long DRAM bursts, page-hit reads.
    f4 r[NIT];
    #pragma unroll
    for (int i = 0; i < NIT; ++i) {
        const int v  = min(t + i * NT, NV - 1);      // clamp: dup loads benign
        const int c  = v / Q;
        const int pq = v - c * Q;
        r[i] = *reinterpret_cast<const f4*>(in_plane + c * NPOS + pq * 4);
    }
    // ---- scatter-transpose into LDS (output order: p*NC + c) ----
    #pragma unroll
    for (int i = 0; i < NIT; ++i) {
        const int v  = min(t + i * NT, NV - 1);      // dup writes same value
        const int c  = v / Q;
        const int pq = v - c * Q;
        const int pb = pq * 4;
        lds[(pb + 0) * NC + c] = r[i].x;
        lds[(pb + 1) * NC + c] = r[i].y;
        lds[(pb + 2) * NC + c] = r[i].z;
        lds[(pb + 3) * NC + c] = r[i].w;
    }
    __syncthreads();

    // ---- ds_read_b128 + single-exp branchless transform + coalesced store ----
    for (int v = t; v < NV; v += NT) {
        const int e0 = v * 4;
        const f4 f = *reinterpret_cast<const f4*>(&lds[e0]);
        const int p0 = (int)((unsigned)e0 / (unsigned)NC);   // magic mul
        const int c0 = e0 - p0 * NC;
        // grid coords for row p0 and (possible wrap) p0+1, once per vector
        const int posA = pos0 + p0;
        const int gyA  = (int)((unsigned)posA / (unsigned)NG);
        const int gxA  = posA - gyA * NG;
        const bool wrapRow = (gxA == NG - 1);
        const float gxAf = (float)gxA, gyAf = (float)gyA;
        const float gxBf = wrapRow ? 0.0f : gxAf + 1.0f;
        const float gyBf = wrapRow ? gyAf + 1.0f : gyAf;

        const float xin[4] = {f.x, f.y, f.z, f.w};
        float res[4];
        int p = p0, c = c0;
        #pragma unroll
        for (int k = 0; k < 4; ++k) {
            const float x    = xin[k];
            const bool iswh  = (c == 2) || (c == 3);
            const bool isxy  = (c < 2);
            const float e    = __expf(iswh ? x : -x);   // ONE transcendental
            const float sg   = rcpf(1.0f + e);
            const float gx   = (p != p0) ? gxBf : gxAf;
            const float gy   = (p != p0) ? gyBf : gyAf;
            const float g    = (c == 0) ? gx : gy;
            const float mul  = isxy ? STRIDE_F : (iswh ? ((c == 2) ? aw : ah) : 1.0f);
            const float add  = isxy ? g * STRIDE_F : 0.0f;
            res[k] = fmaf(iswh ? e : sg, mul, add);
            if (++c == NC) { c = 0; ++p; }
        }
        f4 o = {res[0], res[1], res[2], res[3]};
        *reinterpret_cast<f4*>(out_block + e0) = o;
    }
}

__global__ __launch_bounds__(NT) void det_kernel(const float* __restrict__ in,
                                                 float* __restrict__ out) {
    __shared__ __align__(16) float lds[NPB * NC];    // 65280 B -> 2 blocks/CU

    const int bid   = blockIdx.x;
    const int plane = bid / TPP;                     // b*NA + a
    const int tile  = bid - plane * TPP;
    const int a     = plane % NA;
    const int t     = threadIdx.x;
    const float aw = c_aw[a];
    const float ah = c_ah[a];
    const int pos0 = tile * NPB;                     // tail tile: 5760

    const float* in_plane  = in  + (size_t)plane * (NC * NPOS) + pos0;
    float*       out_block = out + (size_t)plane * (NPOS * NC) + (size_t)pos0 * NC;

    if (tile != TILES_MAIN) {                        // block-uniform branch
        process_tile<NPB / 4, 4>(in_plane, out_block, lds, pos0, aw, ah, t);
    } else {                                         // 16-position tail tile
        process_tile<NPB_TAIL / 4, 1>(in_plane, out_block, lds, pos0, aw, ah, t);
    }
}

extern "C" void kernel_launch(void* const* d_in, const int* in_sizes, int n_in,
                              void* d_out, int out_size, void* d_ws, size_t ws_size,
                              hipStream_t stream) {
    const float* x = (const float*)d_in[0];
    float* out     = (float*)d_out;
    const int nB     = in_sizes[0] / (NA * NC * NPOS);   // 16
    const int blocks = nB * NA * TPP;                    // 48 * 31 = 1488
    det_kernel<<<blocks, NT, 0, stream>>>(x, out);
}